// Round 1
// baseline (47581.100 us; speedup 1.0000x reference)
//
#include <hip/hip_runtime.h>
#include <hip/hip_bf16.h>

// LSTM: T=4096, IN=32, H=512, OUT=32, 3 layers + output projection.
// Strategy R1:
//   - Hoist x@W_ih^T + b out of the scan as batched GEMMs (no seq dependency).
//   - Recurrence: persistent 32-WG kernel per layer; W_hh slice register-resident
//     (128 f32/lane); h broadcast from LDS; cross-WG handoff via device-scope
//     flags (correct under per-XCD L2 non-coherence).

#define T_SEQ 4096
#define HDIM  512
#define GDIM  2048   // 4*H gate rows
#define NWG   32     // workgroups per recurrent layer
#define JB    16     // j columns per WG (HDIM / NWG)
#define ROWS  64     // 4*JB gate rows per WG
#define KCH   128    // k-chunk per wave (HDIM / 4 waves)

// ---------------------------------------------------------------------------
// Tiled fp32 GEMM: C[M][N] = A[M][K] * B[N][K]^T + bias1[n] (+ bias2[n])
// M % BM == 0, N % BN == 0, K % BK == 0 for all our shapes.
// ---------------------------------------------------------------------------
template <int BM, int BN, int BK>
__global__ __launch_bounds__(256)
void gemm_abt(const float* __restrict__ A, const float* __restrict__ B,
              const float* __restrict__ bias1, const float* __restrict__ bias2,
              float* __restrict__ C, int M, int N, int K) {
    constexpr int NTX = BN / 4;        // threads along n (each covers 4 cols)
    constexpr int NTY = 256 / NTX;     // threads along m
    constexpr int TM  = BM / NTY;      // rows per thread
    __shared__ float As[BM][BK + 1];
    __shared__ float Bs[BN][BK + 1];

    const int tid = threadIdx.x;
    const int tx = tid % NTX;
    const int ty = tid / NTX;
    const int m0 = blockIdx.y * BM;
    const int n0 = blockIdx.x * BN;

    float acc[TM][4];
    #pragma unroll
    for (int i = 0; i < TM; ++i)
        #pragma unroll
        for (int j = 0; j < 4; ++j) acc[i][j] = 0.f;

    for (int k0 = 0; k0 < K; k0 += BK) {
        constexpr int AV = BM * BK / 4;   // float4 loads for A tile
        #pragma unroll
        for (int i = tid; i < AV; i += 256) {
            int r = i / (BK / 4), c4 = i % (BK / 4);
            float4 v = *(const float4*)(A + (size_t)(m0 + r) * K + k0 + c4 * 4);
            As[r][c4 * 4 + 0] = v.x; As[r][c4 * 4 + 1] = v.y;
            As[r][c4 * 4 + 2] = v.z; As[r][c4 * 4 + 3] = v.w;
        }
        constexpr int BV = BN * BK / 4;
        #pragma unroll
        for (int i = tid; i < BV; i += 256) {
            int r = i / (BK / 4), c4 = i % (BK / 4);
            float4 v = *(const float4*)(B + (size_t)(n0 + r) * K + k0 + c4 * 4);
            Bs[r][c4 * 4 + 0] = v.x; Bs[r][c4 * 4 + 1] = v.y;
            Bs[r][c4 * 4 + 2] = v.z; Bs[r][c4 * 4 + 3] = v.w;
        }
        __syncthreads();
        #pragma unroll
        for (int kk = 0; kk < BK; ++kk) {
            float a[TM], b[4];
            #pragma unroll
            for (int i = 0; i < TM; ++i) a[i] = As[ty * TM + i][kk];
            #pragma unroll
            for (int j = 0; j < 4; ++j) b[j] = Bs[tx * 4 + j][kk];
            #pragma unroll
            for (int i = 0; i < TM; ++i)
                #pragma unroll
                for (int j = 0; j < 4; ++j) acc[i][j] += a[i] * b[j];
        }
        __syncthreads();
    }

    #pragma unroll
    for (int j = 0; j < 4; ++j) {
        int n = n0 + tx * 4 + j;
        float bv = bias1 ? bias1[n] : 0.f;
        if (bias2) bv += bias2[n];
        #pragma unroll
        for (int i = 0; i < TM; ++i) acc[i][j] += bv;
    }
    #pragma unroll
    for (int i = 0; i < TM; ++i) {
        int m = m0 + ty * TM + i;
        float4 v = make_float4(acc[i][0], acc[i][1], acc[i][2], acc[i][3]);
        *(float4*)(C + (size_t)m * N + n0 + tx * 4) = v;
    }
}

// ---------------------------------------------------------------------------
// Persistent recurrent layer. 32 WGs x 256 threads. WG g owns j in
// [g*JB, g*JB+JB); its 64 gate rows are gate*512 + g*JB + jl, gate in {i,f,g,o}.
// Wave w owns k-chunk [w*128, w*128+128). Lane = local row (gate*16+jl).
// Weights live in 128 VGPRs per lane. h exchanged via global hs + flag counter.
// ---------------------------------------------------------------------------
__global__ __launch_bounds__(256, 1)
void lstm_rec(const float* __restrict__ X,    // [T][2048] precomputed x@Wih^T + b
              const float* __restrict__ Whh,  // [2048][512]
              float* __restrict__ hs,         // [T][512] output h sequence
              int* __restrict__ flags,        // [T], zeroed before launch
              int T) {
    __shared__ float h_lds[HDIM];
    __shared__ float part[4 * ROWS];

    const int tid  = threadIdx.x;
    const int wave = tid >> 6;
    const int lane = tid & 63;
    const int g    = blockIdx.x;

    const int gate = lane >> 4;   // 0..3
    const int jl   = lane & 15;   // 0..15
    const int grow = gate * HDIM + g * JB + jl;   // global gate row

    // Load this lane's weight strip into registers (one-time, 4 MB total).
    float w[KCH];
    const float* wp = Whh + (size_t)grow * HDIM + wave * KCH;
    #pragma unroll
    for (int m = 0; m < KCH / 4; ++m) {
        float4 v = ((const float4*)wp)[m];
        w[4 * m + 0] = v.x; w[4 * m + 1] = v.y;
        w[4 * m + 2] = v.z; w[4 * m + 3] = v.w;
    }

    float c = 0.f;   // cell state, lanes 0..15 of wave 0 only

    for (int t = 0; t < T; ++t) {
        if (t == 0) {
            for (int i = tid; i < HDIM; i += 256) h_lds[i] = 0.f;
        } else {
            if (tid == 0) {
                while (__hip_atomic_load(flags + (t - 1), __ATOMIC_RELAXED,
                                         __HIP_MEMORY_SCOPE_AGENT) < NWG) {}
            }
            __syncthreads();
            __builtin_amdgcn_fence(__ATOMIC_ACQUIRE, "agent");
            if (tid < HDIM / 4) {
                float4 hv = ((const float4*)(hs + (size_t)(t - 1) * HDIM))[tid];
                ((float4*)h_lds)[tid] = hv;
            }
        }
        __syncthreads();

        // Partial dot: this wave's 128-k chunk for all 64 rows.
        float p = 0.f;
        const float4* h4 = ((const float4*)h_lds) + wave * (KCH / 4);
        #pragma unroll
        for (int m = 0; m < KCH / 4; ++m) {
            float4 hv = h4[m];   // broadcast read: all lanes same address
            p += w[4 * m + 0] * hv.x;
            p += w[4 * m + 1] * hv.y;
            p += w[4 * m + 2] * hv.z;
            p += w[4 * m + 3] * hv.w;
        }
        part[wave * ROWS + lane] = p;
        __syncthreads();

        if (tid < 64) {
            float tot = X[(size_t)t * GDIM + grow]
                      + part[lane] + part[64 + lane]
                      + part[128 + lane] + part[192 + lane];
            // Gather the 4 gates of column jl to lanes 0..15.
            float ai = __shfl(tot, jl +  0, 64);
            float af = __shfl(tot, jl + 16, 64);
            float ag = __shfl(tot, jl + 32, 64);
            float ao = __shfl(tot, jl + 48, 64);
            if (lane < 16) {
                float iv = 1.f / (1.f + __expf(-ai));
                float fv = 1.f / (1.f + __expf(-af));
                float gv = tanhf(ag);
                float ov = 1.f / (1.f + __expf(-ao));
                c = fv * c + iv * gv;
                float h = ov * tanhf(c);
                hs[(size_t)t * HDIM + g * JB + lane] = h;
            }
            __builtin_amdgcn_fence(__ATOMIC_RELEASE, "agent");
            if (tid == 0) {
                __hip_atomic_fetch_add(flags + t, 1, __ATOMIC_RELEASE,
                                       __HIP_MEMORY_SCOPE_AGENT);
            }
        }
        // next iteration's first barrier orders everyone behind the producer
    }
}

// ---------------------------------------------------------------------------
extern "C" void kernel_launch(void* const* d_in, const int* in_sizes, int n_in,
                              void* d_out, int out_size, void* d_ws, size_t ws_size,
                              hipStream_t stream) {
    const float* seq   = (const float*)d_in[0];
    const float* W_ih1 = (const float*)d_in[1];
    const float* W_hh1 = (const float*)d_in[2];
    const float* b_ih1 = (const float*)d_in[3];
    const float* b_hh1 = (const float*)d_in[4];
    const float* W_ih2 = (const float*)d_in[5];
    const float* W_hh2 = (const float*)d_in[6];
    const float* b_ih2 = (const float*)d_in[7];
    const float* b_hh2 = (const float*)d_in[8];
    const float* W_ih3 = (const float*)d_in[9];
    const float* W_hh3 = (const float*)d_in[10];
    const float* b_ih3 = (const float*)d_in[11];
    const float* b_hh3 = (const float*)d_in[12];
    const float* W_out = (const float*)d_in[13];
    const float* b_out = (const float*)d_in[14];
    float* out = (float*)d_out;

    // Workspace layout (floats): X[T][2048], hA[T][512], hB[T][512], flags[3*T]
    float* X  = (float*)d_ws;
    float* hA = X  + (size_t)T_SEQ * GDIM;
    float* hB = hA + (size_t)T_SEQ * HDIM;
    int* flags = (int*)(hB + (size_t)T_SEQ * HDIM);

    hipMemsetAsync(flags, 0, 3 * T_SEQ * sizeof(int), stream);

    dim3 gX(GDIM / 64, T_SEQ / 64);

    // Layer 1: X = seq @ W_ih1^T + b ; recurrence -> hA
    gemm_abt<64, 64, 32><<<gX, 256, 0, stream>>>(seq, W_ih1, b_ih1, b_hh1, X,
                                                 T_SEQ, GDIM, 32);
    lstm_rec<<<NWG, 256, 0, stream>>>(X, W_hh1, hA, flags + 0 * T_SEQ, T_SEQ);

    // Layer 2: X = hA @ W_ih2^T + b ; recurrence -> hB
    gemm_abt<64, 64, 32><<<gX, 256, 0, stream>>>(hA, W_ih2, b_ih2, b_hh2, X,
                                                 T_SEQ, GDIM, HDIM);
    lstm_rec<<<NWG, 256, 0, stream>>>(X, W_hh2, hB, flags + 1 * T_SEQ, T_SEQ);

    // Layer 3: X = hB @ W_ih3^T + b ; recurrence -> hA (reuse)
    gemm_abt<64, 64, 32><<<gX, 256, 0, stream>>>(hB, W_ih3, b_ih3, b_hh3, X,
                                                 T_SEQ, GDIM, HDIM);
    lstm_rec<<<NWG, 256, 0, stream>>>(X, W_hh3, hA, flags + 2 * T_SEQ, T_SEQ);

    // Output projection: out = hA @ W_out^T + b_out
    gemm_abt<64, 32, 32><<<dim3(1, T_SEQ / 64), 256, 0, stream>>>(
        hA, W_out, b_out, nullptr, out, T_SEQ, 32, HDIM);
}

// Round 2
// 34605.875 us; speedup vs baseline: 1.3749x; 1.3749x over previous
//
#include <hip/hip_runtime.h>
#include <hip/hip_bf16.h>

// LSTM T=4096, IN=32, H=512, OUT=32, 3 layers + projection.
// R2: single persistent kernel pipelines all 3 layers (96 WGs x 512 thr).
//   - Layer 0: gates = X1[t] (precomputed GEMM, incl. biases) + Whh1*h0[t-1]
//   - Layers 1/2: gates = bias + [Wih|Whh] * [h_prev_layer[t]; h_own[t-1]]
//   - Weights register-resident (<=128 f32/lane).
//   - Sync: per-producer flag words (no RMW) + 64-lane parallel poll;
//     agent-scope release/acquire fences (correct under XCD L2 non-coherence).

#define T_SEQ 4096
#define HDIM  512
#define GDIM  2048
#define NWG_L 32      // WGs per layer
#define JB    16      // h columns per WG
#define NTH   512     // threads per WG (8 waves)

// ---------------------------------------------------------------------------
// Tiled fp32 GEMM: C[M][N] = A[M][K] * B[N][K]^T + bias1[n] (+ bias2[n])
// ---------------------------------------------------------------------------
template <int BM, int BN, int BK>
__global__ __launch_bounds__(256)
void gemm_abt(const float* __restrict__ A, const float* __restrict__ B,
              const float* __restrict__ bias1, const float* __restrict__ bias2,
              float* __restrict__ C, int M, int N, int K) {
    constexpr int NTX = BN / 4;
    constexpr int NTY = 256 / NTX;
    constexpr int TM  = BM / NTY;
    __shared__ float As[BM][BK + 1];
    __shared__ float Bs[BN][BK + 1];

    const int tid = threadIdx.x;
    const int tx = tid % NTX;
    const int ty = tid / NTX;
    const int m0 = blockIdx.y * BM;
    const int n0 = blockIdx.x * BN;

    float acc[TM][4];
    #pragma unroll
    for (int i = 0; i < TM; ++i)
        #pragma unroll
        for (int j = 0; j < 4; ++j) acc[i][j] = 0.f;

    for (int k0 = 0; k0 < K; k0 += BK) {
        constexpr int AV = BM * BK / 4;
        #pragma unroll
        for (int i = tid; i < AV; i += 256) {
            int r = i / (BK / 4), c4 = i % (BK / 4);
            float4 v = *(const float4*)(A + (size_t)(m0 + r) * K + k0 + c4 * 4);
            As[r][c4 * 4 + 0] = v.x; As[r][c4 * 4 + 1] = v.y;
            As[r][c4 * 4 + 2] = v.z; As[r][c4 * 4 + 3] = v.w;
        }
        constexpr int BV = BN * BK / 4;
        #pragma unroll
        for (int i = tid; i < BV; i += 256) {
            int r = i / (BK / 4), c4 = i % (BK / 4);
            float4 v = *(const float4*)(B + (size_t)(n0 + r) * K + k0 + c4 * 4);
            Bs[r][c4 * 4 + 0] = v.x; Bs[r][c4 * 4 + 1] = v.y;
            Bs[r][c4 * 4 + 2] = v.z; Bs[r][c4 * 4 + 3] = v.w;
        }
        __syncthreads();
        #pragma unroll
        for (int kk = 0; kk < BK; ++kk) {
            float a[TM], b[4];
            #pragma unroll
            for (int i = 0; i < TM; ++i) a[i] = As[ty * TM + i][kk];
            #pragma unroll
            for (int j = 0; j < 4; ++j) b[j] = Bs[tx * 4 + j][kk];
            #pragma unroll
            for (int i = 0; i < TM; ++i)
                #pragma unroll
                for (int j = 0; j < 4; ++j) acc[i][j] += a[i] * b[j];
        }
        __syncthreads();
    }

    #pragma unroll
    for (int j = 0; j < 4; ++j) {
        int n = n0 + tx * 4 + j;
        float bv = bias1 ? bias1[n] : 0.f;
        if (bias2) bv += bias2[n];
        #pragma unroll
        for (int i = 0; i < TM; ++i) acc[i][j] += bv;
    }
    #pragma unroll
    for (int i = 0; i < TM; ++i) {
        int m = m0 + ty * TM + i;
        float4 v = make_float4(acc[i][0], acc[i][1], acc[i][2], acc[i][3]);
        *(float4*)(C + (size_t)m * N + n0 + tx * 4) = v;
    }
}

// ---------------------------------------------------------------------------
// Fused 3-layer recurrence. Grid: 96 WGs x 512 threads.
//   b = blockIdx.x; layer = b>>5; g = b&31 owns j in [g*16, g*16+16).
//   64 gate rows per WG: local row = gate*16+jl (lane), grow = gate*512+g*16+jl.
//   Wave w owns k-chunk: layer0 kch=64 over h(512); layers1/2 kch=128 over
//   concat [x(512); h(512)] (waves 0-3 -> Wih, 4-7 -> Whh).
//   flags[layer][t][g] = 1 when h chunk (g*16..+16) of step t is globally
//   visible.
// ---------------------------------------------------------------------------
__global__ __launch_bounds__(NTH, 2)
void lstm_fused(const float* __restrict__ X1,
                const float* __restrict__ Whh1,
                const float* __restrict__ Wih2, const float* __restrict__ Whh2,
                const float* __restrict__ bih2, const float* __restrict__ bhh2,
                const float* __restrict__ Wih3, const float* __restrict__ Whh3,
                const float* __restrict__ bih3, const float* __restrict__ bhh3,
                float* __restrict__ hs0, float* __restrict__ hs1,
                float* __restrict__ hs2,
                int* __restrict__ flags) {
    __shared__ float h_lds[1024];
    __shared__ float part[8 * 64];

    const int b     = blockIdx.x;
    const int layer = b >> 5;
    const int g     = b & 31;
    const int tid   = threadIdx.x;
    const int wave  = tid >> 6;
    const int lane  = tid & 63;
    const int gate  = lane >> 4;
    const int jl    = lane & 15;
    const int grow  = gate * HDIM + g * JB + jl;

    // ---- weight strip into registers (one time) ----
    float w[128];
    if (layer == 0) {
        const float* wp = Whh1 + (size_t)grow * HDIM + wave * 64;
        #pragma unroll
        for (int m = 0; m < 16; ++m) {
            float4 v = ((const float4*)wp)[m];
            w[4*m+0]=v.x; w[4*m+1]=v.y; w[4*m+2]=v.z; w[4*m+3]=v.w;
        }
    } else {
        const float* Wih = (layer == 1) ? Wih2 : Wih3;
        const float* Whh = (layer == 1) ? Whh2 : Whh3;
        const float* wp = (wave < 4)
            ? Wih + (size_t)grow * HDIM + wave * 128
            : Whh + (size_t)grow * HDIM + (wave - 4) * 128;
        #pragma unroll
        for (int m = 0; m < 32; ++m) {
            float4 v = ((const float4*)wp)[m];
            w[4*m+0]=v.x; w[4*m+1]=v.y; w[4*m+2]=v.z; w[4*m+3]=v.w;
        }
    }

    float bsum = 0.f;
    if (layer > 0 && tid < 64) {
        const float* bi = (layer == 1) ? bih2 : bih3;
        const float* bh = (layer == 1) ? bhh2 : bhh3;
        bsum = bi[grow] + bh[grow];
    }

    const float* xin  = (layer == 0) ? nullptr : (layer == 1 ? hs0 : hs1);
    float*       hout = (layer == 0) ? hs0 : (layer == 1 ? hs1 : hs2);
    int*       flagOwn  = flags + (size_t)layer * T_SEQ * NWG_L;
    const int* flagPrev = (layer > 0)
        ? flags + (size_t)(layer - 1) * T_SEQ * NWG_L : nullptr;

    float c = 0.f;   // cell state (wave 0, lanes 0..15)

    for (int t = 0; t < T_SEQ; ++t) {
        // ---- wait for inputs: lanes 0-31 watch input flags, 32-63 own flags
        if (wave == 0) {
            const int* myf = nullptr;
            if (lane < NWG_L) {
                if (layer > 0)      myf = flagPrev + (size_t)t * NWG_L + lane;
                else if (t > 0)     myf = flagOwn + (size_t)(t-1) * NWG_L + lane;
            } else {
                if (layer > 0 && t > 0)
                    myf = flagOwn + (size_t)(t-1) * NWG_L + (lane - NWG_L);
            }
            if (myf) {
                while (__hip_atomic_load(myf, __ATOMIC_RELAXED,
                                         __HIP_MEMORY_SCOPE_AGENT) == 0) {}
            }
        }
        __syncthreads();
        __builtin_amdgcn_fence(__ATOMIC_ACQUIRE, "agent");

        // prefetch the X1 term early (layer 0 finish input)
        float xt = 0.f;
        if (layer == 0 && tid < 64) xt = X1[(size_t)t * GDIM + grow];

        // ---- stage inputs into LDS
        if (layer == 0) {
            h_lds[tid] = (t == 0) ? 0.f : hs0[(size_t)(t-1) * HDIM + tid];
        } else {
            h_lds[tid] = xin[(size_t)t * HDIM + tid];                 // x part
            h_lds[HDIM + tid] = (t == 0)
                ? 0.f : hout[(size_t)(t-1) * HDIM + tid];             // h part
        }
        __syncthreads();

        // ---- partial dot over this wave's k-chunk
        float p = 0.f;
        if (layer == 0) {
            const float4* h4 = (const float4*)(h_lds + wave * 64);
            #pragma unroll
            for (int m = 0; m < 16; ++m) {
                float4 hv = h4[m];
                p += w[4*m+0]*hv.x + w[4*m+1]*hv.y
                   + w[4*m+2]*hv.z + w[4*m+3]*hv.w;
            }
        } else {
            const float4* h4 = (const float4*)(h_lds + wave * 128);
            #pragma unroll
            for (int m = 0; m < 32; ++m) {
                float4 hv = h4[m];
                p += w[4*m+0]*hv.x + w[4*m+1]*hv.y
                   + w[4*m+2]*hv.z + w[4*m+3]*hv.w;
            }
        }
        part[wave * 64 + lane] = p;
        __syncthreads();

        // ---- finish: reduce, gates, publish (wave 0)
        if (tid < 64) {
            float tot = (layer == 0) ? xt : bsum;
            #pragma unroll
            for (int wv = 0; wv < 8; ++wv) tot += part[wv * 64 + lane];
            float ai = __shfl(tot, jl +  0, 64);
            float af = __shfl(tot, jl + 16, 64);
            float ag = __shfl(tot, jl + 32, 64);
            float ao = __shfl(tot, jl + 48, 64);
            if (lane < 16) {
                float iv = 1.f / (1.f + __expf(-ai));
                float fv = 1.f / (1.f + __expf(-af));
                float gv = tanhf(ag);
                float ov = 1.f / (1.f + __expf(-ao));
                c = fv * c + iv * gv;
                float h = ov * tanhf(c);
                hout[(size_t)t * HDIM + g * JB + lane] = h;
            }
            __builtin_amdgcn_fence(__ATOMIC_RELEASE, "agent");
            if (tid == 0) {
                __hip_atomic_store(flagOwn + (size_t)t * NWG_L + g, 1,
                                   __ATOMIC_RELEASE, __HIP_MEMORY_SCOPE_AGENT);
            }
        }
        // next iteration's first barrier protects part[] / h_lds reuse
    }
}

// ---------------------------------------------------------------------------
extern "C" void kernel_launch(void* const* d_in, const int* in_sizes, int n_in,
                              void* d_out, int out_size, void* d_ws, size_t ws_size,
                              hipStream_t stream) {
    const float* seq   = (const float*)d_in[0];
    const float* W_ih1 = (const float*)d_in[1];
    const float* W_hh1 = (const float*)d_in[2];
    const float* b_ih1 = (const float*)d_in[3];
    const float* b_hh1 = (const float*)d_in[4];
    const float* W_ih2 = (const float*)d_in[5];
    const float* W_hh2 = (const float*)d_in[6];
    const float* b_ih2 = (const float*)d_in[7];
    const float* b_hh2 = (const float*)d_in[8];
    const float* W_ih3 = (const float*)d_in[9];
    const float* W_hh3 = (const float*)d_in[10];
    const float* b_ih3 = (const float*)d_in[11];
    const float* b_hh3 = (const float*)d_in[12];
    const float* W_out = (const float*)d_in[13];
    const float* b_out = (const float*)d_in[14];
    float* out = (float*)d_out;

    // Workspace: X1[T][2048], hs0/hs1/hs2[T][512], flags[3][T][32]
    float* X1  = (float*)d_ws;
    float* hs0 = X1  + (size_t)T_SEQ * GDIM;
    float* hs1 = hs0 + (size_t)T_SEQ * HDIM;
    float* hs2 = hs1 + (size_t)T_SEQ * HDIM;
    int* flags = (int*)(hs2 + (size_t)T_SEQ * HDIM);

    hipMemsetAsync(flags, 0, (size_t)3 * T_SEQ * NWG_L * sizeof(int), stream);

    // X1 = seq @ W_ih1^T + (b_ih1 + b_hh1)   [T, 2048], K=32
    gemm_abt<64, 64, 32><<<dim3(GDIM / 64, T_SEQ / 64), 256, 0, stream>>>(
        seq, W_ih1, b_ih1, b_hh1, X1, T_SEQ, GDIM, 32);

    // fused 3-layer recurrence
    lstm_fused<<<3 * NWG_L, NTH, 0, stream>>>(
        X1, W_hh1, W_ih2, W_hh2, b_ih2, b_hh2, W_ih3, W_hh3, b_ih3, b_hh3,
        hs0, hs1, hs2, flags);

    // out = hs2 @ W_out^T + b_out
    gemm_abt<64, 32, 32><<<dim3(1, T_SEQ / 64), 256, 0, stream>>>(
        hs2, W_out, b_out, nullptr, out, T_SEQ, 32, HDIM);
}

// Round 3
// 8299.937 us; speedup vs baseline: 5.7327x; 4.1694x over previous
//
#include <hip/hip_runtime.h>

// LSTM T=4096, IN=32, H=512, OUT=32, 3 layers + projection.
// R3: single persistent kernel, all 3 layers pipelined (96 WGs x 512 thr).
//   - NO cache-wide fences (R2's buffer_inv/wbl2 per step was the killer).
//     All cross-WG traffic is relaxed agent-scope atomics (per-instr sc1,
//     coherent at Infinity Cache, correct under XCD L2 non-coherence).
//   - h published as packed 8B {seq:32 | value:32}: flag IS the data; one
//     atomic store to publish, one polled load to consume.
//   - Weights pinned in VGPRs via asm register constraint (R2 left them in
//     memory: VGPR_Count was 88 < 128).
//   - Layer 0 folds the K=32 input projection into the recurrence (no X1
//     GEMM, no 32MB staging buffer).

#define T_SEQ 4096
#define HDIM  512
#define NWG_L 32
#define JB    16
#define NTH   512

typedef unsigned long long u64;

__device__ __forceinline__ u64 cohLoad(const u64* p) {
    return __hip_atomic_load(p, __ATOMIC_RELAXED, __HIP_MEMORY_SCOPE_AGENT);
}
__device__ __forceinline__ void cohStore(u64* p, u64 v) {
    __hip_atomic_store(p, v, __ATOMIC_RELAXED, __HIP_MEMORY_SCOPE_AGENT);
}

// ---------------------------------------------------------------------------
// Tiled fp32 GEMM (final projection): C[M][N] = A[M][K] * B[N][K]^T + bias[n]
// ---------------------------------------------------------------------------
template <int BM, int BN, int BK>
__global__ __launch_bounds__(256)
void gemm_abt(const float* __restrict__ A, const float* __restrict__ B,
              const float* __restrict__ bias1,
              float* __restrict__ C, int M, int N, int K) {
    constexpr int NTX = BN / 4;
    constexpr int NTY = 256 / NTX;
    constexpr int TM  = BM / NTY;
    __shared__ float As[BM][BK + 1];
    __shared__ float Bs[BN][BK + 1];

    const int tid = threadIdx.x;
    const int tx = tid % NTX;
    const int ty = tid / NTX;
    const int m0 = blockIdx.y * BM;
    const int n0 = blockIdx.x * BN;

    float acc[TM][4];
    #pragma unroll
    for (int i = 0; i < TM; ++i)
        #pragma unroll
        for (int j = 0; j < 4; ++j) acc[i][j] = 0.f;

    for (int k0 = 0; k0 < K; k0 += BK) {
        constexpr int AV = BM * BK / 4;
        #pragma unroll
        for (int i = tid; i < AV; i += 256) {
            int r = i / (BK / 4), c4 = i % (BK / 4);
            float4 v = *(const float4*)(A + (size_t)(m0 + r) * K + k0 + c4 * 4);
            As[r][c4 * 4 + 0] = v.x; As[r][c4 * 4 + 1] = v.y;
            As[r][c4 * 4 + 2] = v.z; As[r][c4 * 4 + 3] = v.w;
        }
        constexpr int BV = BN * BK / 4;
        #pragma unroll
        for (int i = tid; i < BV; i += 256) {
            int r = i / (BK / 4), c4 = i % (BK / 4);
            float4 v = *(const float4*)(B + (size_t)(n0 + r) * K + k0 + c4 * 4);
            Bs[r][c4 * 4 + 0] = v.x; Bs[r][c4 * 4 + 1] = v.y;
            Bs[r][c4 * 4 + 2] = v.z; Bs[r][c4 * 4 + 3] = v.w;
        }
        __syncthreads();
        #pragma unroll
        for (int kk = 0; kk < BK; ++kk) {
            float a[TM], b[4];
            #pragma unroll
            for (int i = 0; i < TM; ++i) a[i] = As[ty * TM + i][kk];
            #pragma unroll
            for (int j = 0; j < 4; ++j) b[j] = Bs[tx * 4 + j][kk];
            #pragma unroll
            for (int i = 0; i < TM; ++i)
                #pragma unroll
                for (int j = 0; j < 4; ++j) acc[i][j] += a[i] * b[j];
        }
        __syncthreads();
    }

    #pragma unroll
    for (int j = 0; j < 4; ++j) {
        float bv = bias1 ? bias1[n0 + tx * 4 + j] : 0.f;
        #pragma unroll
        for (int i = 0; i < TM; ++i) acc[i][j] += bv;
    }
    #pragma unroll
    for (int i = 0; i < TM; ++i) {
        int m = m0 + ty * TM + i;
        float4 v = make_float4(acc[i][0], acc[i][1], acc[i][2], acc[i][3]);
        *(float4*)(C + (size_t)m * N + n0 + tx * 4) = v;
    }
}

// ---------------------------------------------------------------------------
__global__ void unpack_h(const u64* __restrict__ hp, float* __restrict__ out,
                         int n) {
    int i = blockIdx.x * blockDim.x + threadIdx.x;
    if (i < n) out[i] = __uint_as_float((unsigned)hp[i]);
}

// ---------------------------------------------------------------------------
// Fused 3-layer recurrence. 96 WGs x 512 threads; layer = blockIdx>>5,
// g = blockIdx&31 owns h columns [g*16, g*16+16). Lane = gate*16+jl.
// Layer 0: gates = b + Wih1(4Hx32)*x_t + Whh1*h[t-1]   (waves 0-7 split h;
//          wave 0 also does the 32-wide x part)
// Layer 1/2: gates = b + [Wih|Whh] * [hprev_t ; hown_{t-1}]  (K=1024,
//          waves 0-3 -> Wih chunks, 4-7 -> Whh chunks)
// hp[layer][t][col] packed: hi32 = t+1 (seq), lo32 = float bits of h.
// ---------------------------------------------------------------------------
__global__ __launch_bounds__(NTH, 2)
void lstm_fused(const float* __restrict__ seq,
                const float* __restrict__ Wih1, const float* __restrict__ Whh1,
                const float* __restrict__ bih1, const float* __restrict__ bhh1,
                const float* __restrict__ Wih2, const float* __restrict__ Whh2,
                const float* __restrict__ bih2, const float* __restrict__ bhh2,
                const float* __restrict__ Wih3, const float* __restrict__ Whh3,
                const float* __restrict__ bih3, const float* __restrict__ bhh3,
                u64* __restrict__ hp) {
    __shared__ __align__(16) float h_lds[2 * HDIM];
    __shared__ __align__(16) float x_lds[32];
    __shared__ float part[8 * 64];

    const int b     = blockIdx.x;
    const int layer = b >> 5;
    const int g     = b & 31;
    const int tid   = threadIdx.x;
    const int wave  = tid >> 6;
    const int lane  = tid & 63;
    const int gate  = lane >> 4;
    const int jl    = lane & 15;
    const int grow  = gate * HDIM + g * JB + jl;

    const float* Wih = layer == 0 ? Wih1 : (layer == 1 ? Wih2 : Wih3);
    const float* Whh = layer == 0 ? Whh1 : (layer == 1 ? Whh2 : Whh3);
    const float* bih = layer == 0 ? bih1 : (layer == 1 ? bih2 : bih3);
    const float* bhh = layer == 0 ? bhh1 : (layer == 1 ? bhh2 : bhh3);

    // ---- weights into registers ----
    float w[128];
    #pragma unroll
    for (int m = 0; m < 128; ++m) w[m] = 0.f;
    if (layer == 0) {
        const float* wp = Whh + (size_t)grow * HDIM + wave * 64;
        #pragma unroll
        for (int m = 0; m < 16; ++m) {
            float4 v = ((const float4*)wp)[m];
            w[4*m+0]=v.x; w[4*m+1]=v.y; w[4*m+2]=v.z; w[4*m+3]=v.w;
        }
        if (wave == 0) {   // x-projection row (K=32) lives in w[64..95]
            const float* xp = Wih + (size_t)grow * 32;
            #pragma unroll
            for (int m = 0; m < 8; ++m) {
                float4 v = ((const float4*)xp)[m];
                w[64+4*m]=v.x; w[65+4*m]=v.y; w[66+4*m]=v.z; w[67+4*m]=v.w;
            }
        }
    } else {
        const float* wp = (wave < 4)
            ? Wih + (size_t)grow * HDIM + wave * 128
            : Whh + (size_t)grow * HDIM + (wave - 4) * 128;
        #pragma unroll
        for (int m = 0; m < 32; ++m) {
            float4 v = ((const float4*)wp)[m];
            w[4*m+0]=v.x; w[4*m+1]=v.y; w[4*m+2]=v.z; w[4*m+3]=v.w;
        }
    }
    // Pin in VGPRs: loads cannot be sunk into the loop past this point.
    #pragma unroll
    for (int m = 0; m < 128; ++m) asm volatile("" : "+v"(w[m]));

    float bsum = 0.f;
    if (tid < 64) bsum = bih[grow] + bhh[grow];

    u64*       hpOwn  = hp + (size_t)layer * T_SEQ * HDIM;
    const u64* hpPrev = hp + (size_t)(layer > 0 ? layer - 1 : 0) * T_SEQ * HDIM;

    float c = 0.f;   // cell state (wave 0, lanes 0..15)

    for (unsigned t = 0; t < T_SEQ; ++t) {
        // ---- stage inputs (poll fused with data read) ----
        if (layer == 0) {
            if (wave == 7 && lane < 32)
                x_lds[lane] = seq[(size_t)t * 32 + lane];
            float hv = 0.f;
            if (t > 0) {
                const u64* ph = hpOwn + (size_t)(t - 1) * HDIM + tid;
                u64 v;
                do { v = cohLoad(ph); } while ((unsigned)(v >> 32) != t);
                hv = __uint_as_float((unsigned)v);
            }
            h_lds[tid] = hv;
        } else {
            const u64* px = hpPrev + (size_t)t * HDIM + tid;
            u64 va;
            if (t > 0) {
                const u64* ph = hpOwn + (size_t)(t - 1) * HDIM + tid;
                u64 vb; bool ra = false, rb = false;
                for (;;) {
                    if (!ra) { va = cohLoad(px); ra = ((unsigned)(va >> 32) == t + 1u); }
                    if (!rb) { vb = cohLoad(ph); rb = ((unsigned)(vb >> 32) == t); }
                    if (ra & rb) break;
                }
                h_lds[HDIM + tid] = __uint_as_float((unsigned)vb);
            } else {
                do { va = cohLoad(px); } while ((unsigned)(va >> 32) != 1u);
                h_lds[HDIM + tid] = 0.f;
            }
            h_lds[tid] = __uint_as_float((unsigned)va);
        }
        __syncthreads();

        // ---- partial dot over this wave's k-chunk ----
        float p = 0.f;
        if (layer == 0) {
            const float4* h4 = (const float4*)(h_lds + wave * 64);
            #pragma unroll
            for (int m = 0; m < 16; ++m) {
                float4 hv = h4[m];
                p += w[4*m+0]*hv.x + w[4*m+1]*hv.y
                   + w[4*m+2]*hv.z + w[4*m+3]*hv.w;
            }
            if (wave == 0) {
                const float4* x4 = (const float4*)x_lds;
                #pragma unroll
                for (int m = 0; m < 8; ++m) {
                    float4 xv = x4[m];
                    p += w[64+4*m]*xv.x + w[65+4*m]*xv.y
                       + w[66+4*m]*xv.z + w[67+4*m]*xv.w;
                }
            }
        } else {
            const float4* h4 = (const float4*)(h_lds + wave * 128);
            #pragma unroll
            for (int m = 0; m < 32; ++m) {
                float4 hv = h4[m];
                p += w[4*m+0]*hv.x + w[4*m+1]*hv.y
                   + w[4*m+2]*hv.z + w[4*m+3]*hv.w;
            }
        }
        part[wave * 64 + lane] = p;
        __syncthreads();

        // ---- finish: reduce, gates, publish (wave 0) ----
        if (tid < 64) {
            float tot = bsum;
            #pragma unroll
            for (int wv = 0; wv < 8; ++wv) tot += part[wv * 64 + lane];
            float ai = __shfl(tot, jl +  0, 64);
            float af = __shfl(tot, jl + 16, 64);
            float ag = __shfl(tot, jl + 32, 64);
            float ao = __shfl(tot, jl + 48, 64);
            if (lane < 16) {
                float iv = __builtin_amdgcn_rcpf(1.f + __expf(-ai));
                float fv = __builtin_amdgcn_rcpf(1.f + __expf(-af));
                float gv = tanhf(ag);
                float ov = __builtin_amdgcn_rcpf(1.f + __expf(-ao));
                c = fv * c + iv * gv;
                float h = ov * tanhf(c);
                u64 pkt = (u64)__float_as_uint(h) | ((u64)(t + 1u) << 32);
                cohStore(hpOwn + (size_t)t * HDIM + g * JB + lane, pkt);
            }
        }
        // 2 barriers/step: next iteration's B1 protects part[]/h_lds reuse.
    }
}

// ---------------------------------------------------------------------------
extern "C" void kernel_launch(void* const* d_in, const int* in_sizes, int n_in,
                              void* d_out, int out_size, void* d_ws, size_t ws_size,
                              hipStream_t stream) {
    const float* seq   = (const float*)d_in[0];
    const float* W_ih1 = (const float*)d_in[1];
    const float* W_hh1 = (const float*)d_in[2];
    const float* b_ih1 = (const float*)d_in[3];
    const float* b_hh1 = (const float*)d_in[4];
    const float* W_ih2 = (const float*)d_in[5];
    const float* W_hh2 = (const float*)d_in[6];
    const float* b_ih2 = (const float*)d_in[7];
    const float* b_hh2 = (const float*)d_in[8];
    const float* W_ih3 = (const float*)d_in[9];
    const float* W_hh3 = (const float*)d_in[10];
    const float* b_ih3 = (const float*)d_in[11];
    const float* b_hh3 = (const float*)d_in[12];
    const float* W_out = (const float*)d_in[13];
    const float* b_out = (const float*)d_in[14];
    float* out = (float*)d_out;

    // Workspace: hp[3][T][512] packed u64 (50.3MB). hs2 floats reuse the
    // layer-0 packed region after the recurrence finishes.
    u64*   hp   = (u64*)d_ws;
    float* hs2f = (float*)d_ws;                       // dead layer-0 region
    const u64* hp2 = hp + (size_t)2 * T_SEQ * HDIM;   // layer-2 packed

    hipMemsetAsync(hp, 0, (size_t)3 * T_SEQ * HDIM * sizeof(u64), stream);

    lstm_fused<<<3 * NWG_L, NTH, 0, stream>>>(
        seq, W_ih1, W_hh1, b_ih1, b_hh1, W_ih2, W_hh2, b_ih2, b_hh2,
        W_ih3, W_hh3, b_ih3, b_hh3, hp);

    const int n = T_SEQ * HDIM;
    unpack_h<<<(n + 255) / 256, 256, 0, stream>>>(hp2, hs2f, n);

    gemm_abt<64, 32, 32><<<dim3(1, T_SEQ / 64), 256, 0, stream>>>(
        hs2f, W_out, b_out, out, T_SEQ, 32, HDIM);
}